// Round 3
// baseline (130.936 us; speedup 1.0000x reference)
//
#include <hip/hip_runtime.h>

// PINN fused forward + u_x + u_xx for a 1->10->10->10->1 tanh MLP.
// Round 3:
//  - NO LDS: every weight/bias is wave-uniform with literal indices, so the
//    compiler scalarizes the loads (s_load -> SGPR) and the matvec FMAs take
//    the weight as the single allowed SGPR operand. Removes staging, barrier,
//    ds_reads, and the VGPR copies of weight rows.
//  - __launch_bounds__(256,2): relax the round-2 (256,4) pressure target that
//    forced 44 arch VGPRs against ~60 live values (AGPR shuffle bloat).
//  - tanh jet in 6 ops incl. 2 trans: e=exp2(z*2log2e); r=rcp(1+e);
//    t=fma(-2,r,1); d=sech^2=fma(-t,t,1).

#define H 10

#if defined(__has_builtin)
#if __has_builtin(__builtin_amdgcn_exp2f)
#define EXP2F(v) __builtin_amdgcn_exp2f(v)
#else
#define EXP2F(v) exp2f(v)
#endif
#else
#define EXP2F(v) exp2f(v)
#endif

// exp(2z) = 2^(z * 2*log2(e))
#define TWO_LOG2E 2.885390082f

#define TANH_TD(z, t, d)                                  \
    {                                                     \
        const float e_ = EXP2F((z) * TWO_LOG2E);          \
        const float r_ = __builtin_amdgcn_rcpf(1.f + e_); \
        (t) = fmaf(-2.f, r_, 1.f);                        \
        (d) = fmaf(-(t), (t), 1.f);                       \
    }

__global__ __launch_bounds__(256, 2) void pinn_fused(
    const float* __restrict__ x,
    const float* __restrict__ W1, const float* __restrict__ b1,
    const float* __restrict__ W2, const float* __restrict__ b2,
    const float* __restrict__ W3, const float* __restrict__ b3,
    const float* __restrict__ W4,
    float* __restrict__ out, int n)
{
    const int i = blockIdx.x * 256 + threadIdx.x;
    if (i >= n) return;
    const float xv = x[i];

    // per-node jet state: t (value), g (d/dx), s (d2/dx2)
    float t_[H], g_[H], s_[H];

    // ---- layer 1: z = x*w + b ; z' = w ; z'' = 0 ----
    // s1 = -2 t d w^2 = -2 * (t*g) * w  with g = d*w
#pragma unroll
    for (int j = 0; j < H; ++j) {
        const float w = W1[j];
        const float z = fmaf(xv, w, b1[j]);
        float t, d;
        TANH_TD(z, t, d);
        const float g = d * w;
        const float y = (t * g) * w;
        t_[j] = t;
        g_[j] = g;
        s_[j] = -(y + y);
    }

    // ---- hidden layers (weights direct from global -> SGPR operands) ----
#define HIDDEN_LAYER(W, B)                                                    \
    {                                                                         \
        float z_[H], p_[H], q_[H];                                            \
        {   /* j == 0 folds accumulator init */                               \
            const float tj = t_[0], gj = g_[0], sj = s_[0];                   \
            _Pragma("unroll")                                                 \
            for (int k = 0; k < H; ++k) {                                     \
                const float w = W[k];                                         \
                z_[k] = fmaf(tj, w, B[k]);                                    \
                p_[k] = gj * w;                                               \
                q_[k] = sj * w;                                               \
            }                                                                 \
        }                                                                     \
        _Pragma("unroll")                                                     \
        for (int j = 1; j < H; ++j) {                                         \
            const float tj = t_[j], gj = g_[j], sj = s_[j];                   \
            _Pragma("unroll")                                                 \
            for (int k = 0; k < H; ++k) {                                     \
                const float w = W[j * H + k];                                 \
                z_[k] = fmaf(tj, w, z_[k]);                                   \
                p_[k] = fmaf(gj, w, p_[k]);                                   \
                q_[k] = fmaf(sj, w, q_[k]);                                   \
            }                                                                 \
        }                                                                     \
        _Pragma("unroll")                                                     \
        for (int k = 0; k < H; ++k) {                                         \
            const float p = p_[k], q = q_[k];                                 \
            float t, d;                                                       \
            TANH_TD(z_[k], t, d);                                             \
            const float g = d * p;                                            \
            const float dq = d * q;                                           \
            const float m = (t + t) * p;                                      \
            t_[k] = t;                                                        \
            g_[k] = g;                                                        \
            s_[k] = fmaf(-m, g, dq);                                          \
        }                                                                     \
    }

    HIDDEN_LAYER(W2, b2)
    HIDDEN_LAYER(W3, b3)
#undef HIDDEN_LAYER

    // ---- output layer: u = h3 @ W4 (no bias) ----
    float u, ux, uxx;
    {
        const float w0 = W4[0];
        u = t_[0] * w0; ux = g_[0] * w0; uxx = s_[0] * w0;
    }
#pragma unroll
    for (int k = 1; k < H; ++k) {
        const float w = W4[k];
        u   = fmaf(t_[k], w, u);
        ux  = fmaf(g_[k], w, ux);
        uxx = fmaf(s_[k], w, uxx);
    }

    float* o = out + i * 3;
    o[0] = u; o[1] = ux; o[2] = uxx;
}

extern "C" void kernel_launch(void* const* d_in, const int* in_sizes, int n_in,
                              void* d_out, int out_size, void* d_ws, size_t ws_size,
                              hipStream_t stream) {
    const float* x  = (const float*)d_in[0];
    const float* W1 = (const float*)d_in[1];
    const float* b1 = (const float*)d_in[2];
    const float* W2 = (const float*)d_in[3];
    const float* b2 = (const float*)d_in[4];
    const float* W3 = (const float*)d_in[5];
    const float* b3 = (const float*)d_in[6];
    const float* W4 = (const float*)d_in[7];
    float* out = (float*)d_out;

    const int n = in_sizes[0];
    const int threads = 256;
    const int blocks = (n + threads - 1) / threads;
    pinn_fused<<<blocks, threads, 0, stream>>>(x, W1, b1, W2, b2, W3, b3, W4, out, n);
}

// Round 4
// 128.627 us; speedup vs baseline: 1.0180x; 1.0180x over previous
//
#include <hip/hip_runtime.h>

// PINN fused forward + u_x + u_xx for a 1->10->10->10->1 tanh MLP.
// Round 4: round-2 LDS structure + amdgpu_waves_per_eu(4,4) to pin the
// register allocator at a 128-VGPR budget (4 waves/EU min AND max). Rounds
// 1-3 all showed the allocator targeting high occupancy on its own, parking
// ~60 live jet values in AGPRs and burning ~half the VALU issue slots on
// v_accvgpr copies (R3: VGPR_Count=28 for ~85 live values, 2135 instr/wave
// vs ~1000 algorithmic).
//  - weights staged once/block to LDS; W2/W3 rows padded to 12 floats so a
//    row = 3x ds_read_b128, broadcast (0 bank conflicts measured).
//  - tanh jet: e=exp2(z*2log2e); r=rcp(1+e); t=fma(-2,r,1); d=fma(-t,t,1).
//  - output layer fused into layer-3 activation (3 scalars instead of 30).

#define H  10
#define RS 12

#define TWO_LOG2E 2.885390082f

#define TANH_TD(z, t, d)                                  \
    {                                                     \
        const float e_ = exp2f((z) * TWO_LOG2E);          \
        const float r_ = __builtin_amdgcn_rcpf(1.f + e_); \
        (t) = fmaf(-2.f, r_, 1.f);                        \
        (d) = fmaf(-(t), (t), 1.f);                       \
    }

__global__
__attribute__((amdgpu_flat_work_group_size(256, 256)))
__attribute__((amdgpu_waves_per_eu(4, 4)))
void pinn_fused(
    const float* __restrict__ x,
    const float* __restrict__ W1, const float* __restrict__ b1,
    const float* __restrict__ W2, const float* __restrict__ b2,
    const float* __restrict__ W3, const float* __restrict__ b3,
    const float* __restrict__ W4,
    float* __restrict__ out, int n)
{
    __shared__ __align__(16) float sW2[H * RS];
    __shared__ __align__(16) float sW3[H * RS];
    __shared__ float sW1[H], sB1[H], sB2[H], sB3[H], sW4[H];

    const int tid = threadIdx.x;
    if (tid < H * RS) {
        const int r = tid / RS, c = tid - r * RS;
        sW2[tid] = (c < H) ? W2[r * H + c] : 0.f;
        sW3[tid] = (c < H) ? W3[r * H + c] : 0.f;
    }
    if (tid < H) {
        sW1[tid] = W1[tid];
        sB1[tid] = b1[tid];
        sB2[tid] = b2[tid];
        sB3[tid] = b3[tid];
        sW4[tid] = W4[tid];
    }
    __syncthreads();

    const int i = blockIdx.x * 256 + tid;
    if (i >= n) return;
    const float xv = x[i];

    // per-node jet state: t (value), g (d/dx), s (d2/dx2)
    float t_[H], g_[H], s_[H];

    // ---- layer 1: z = x*w + b ; z' = w ; z'' = 0 ----
    // s1 = -2 t d w^2 = -2 * (t*g) * w  with g = d*w
#pragma unroll
    for (int j = 0; j < H; ++j) {
        const float w = sW1[j];
        const float z = fmaf(xv, w, sB1[j]);
        float t, d;
        TANH_TD(z, t, d);
        const float g = d * w;
        const float y = (t * g) * w;
        t_[j] = t;
        g_[j] = g;
        s_[j] = -(y + y);
    }

    // ---- layer 2 (matvec from LDS rows + tanh jet) ----
    float z_[H], p_[H], q_[H];
#define MATVEC(SW, SB)                                                        \
    {                                                                         \
        {   /* j == 0 folds accumulator init */                               \
            const float4* row = (const float4*)(SW);                          \
            const float4 w0 = row[0], w1v = row[1], w2v = row[2];             \
            const float wr[H] = {w0.x, w0.y, w0.z, w0.w,                      \
                                 w1v.x, w1v.y, w1v.z, w1v.w,                  \
                                 w2v.x, w2v.y};                               \
            const float tj = t_[0], gj = g_[0], sj = s_[0];                   \
            _Pragma("unroll")                                                 \
            for (int k = 0; k < H; ++k) {                                     \
                z_[k] = fmaf(tj, wr[k], SB[k]);                               \
                p_[k] = gj * wr[k];                                           \
                q_[k] = sj * wr[k];                                           \
            }                                                                 \
        }                                                                     \
        _Pragma("unroll")                                                     \
        for (int j = 1; j < H; ++j) {                                         \
            const float4* row = (const float4*)(SW + j * RS);                 \
            const float4 w0 = row[0], w1v = row[1], w2v = row[2];             \
            const float wr[H] = {w0.x, w0.y, w0.z, w0.w,                      \
                                 w1v.x, w1v.y, w1v.z, w1v.w,                  \
                                 w2v.x, w2v.y};                               \
            const float tj = t_[j], gj = g_[j], sj = s_[j];                   \
            _Pragma("unroll")                                                 \
            for (int k = 0; k < H; ++k) {                                     \
                z_[k] = fmaf(tj, wr[k], z_[k]);                               \
                p_[k] = fmaf(gj, wr[k], p_[k]);                               \
                q_[k] = fmaf(sj, wr[k], q_[k]);                               \
            }                                                                 \
        }                                                                     \
    }

    MATVEC(sW2, sB2)
#pragma unroll
    for (int k = 0; k < H; ++k) {
        const float p = p_[k], q = q_[k];
        float t, d;
        TANH_TD(z_[k], t, d);
        const float g = d * p;
        const float dq = d * q;
        const float m = (t + t) * p;
        t_[k] = t;
        g_[k] = g;
        s_[k] = fmaf(-m, g, dq);
    }

    // ---- layer 3 matvec, then fused tanh-jet + output dot ----
    MATVEC(sW3, sB3)
#undef MATVEC

    float u = 0.f, ux = 0.f, uxx = 0.f;
#pragma unroll
    for (int k = 0; k < H; ++k) {
        const float p = p_[k], q = q_[k];
        float t, d;
        TANH_TD(z_[k], t, d);
        const float g = d * p;
        const float dq = d * q;
        const float m = (t + t) * p;
        const float s = fmaf(-m, g, dq);
        const float w = sW4[k];
        u   = fmaf(t, w, u);
        ux  = fmaf(g, w, ux);
        uxx = fmaf(s, w, uxx);
    }

    float* o = out + i * 3;
    o[0] = u; o[1] = ux; o[2] = uxx;
}

extern "C" void kernel_launch(void* const* d_in, const int* in_sizes, int n_in,
                              void* d_out, int out_size, void* d_ws, size_t ws_size,
                              hipStream_t stream) {
    const float* x  = (const float*)d_in[0];
    const float* W1 = (const float*)d_in[1];
    const float* b1 = (const float*)d_in[2];
    const float* W2 = (const float*)d_in[3];
    const float* b2 = (const float*)d_in[4];
    const float* W3 = (const float*)d_in[5];
    const float* b3 = (const float*)d_in[6];
    const float* W4 = (const float*)d_in[7];
    float* out = (float*)d_out;

    const int n = in_sizes[0];
    const int threads = 256;
    const int blocks = (n + threads - 1) / threads;
    pinn_fused<<<blocks, threads, 0, stream>>>(x, W1, b1, W2, b2, W3, b3, W4, out, n);
}

// Round 5
// 113.509 us; speedup vs baseline: 1.1535x; 1.1332x over previous
//
#include <hip/hip_runtime.h>

// PINN fused forward + u_x + u_xx for a 1->10->10->10->1 tanh MLP.
// Round 5: packed-FP32 (VOP3P v_pk_fma_f32) — 2 samples/thread as float2
// ext-vectors via __builtin_elementwise_fma. Halves the FMA/mul instruction
// count per sample; wave-uniform weight splats fold into VOP3P op_sel.
// waves_per_eu(3,3) pins a 168-VGPR budget so the ~145 live regs fit in
// arch VGPRs with no AGPR spill traffic (the R1-R4 2x issue-slot overhead).
//  - weights staged once/block to LDS; W2/W3 rows padded to 12 floats so a
//    row = 3x ds_read_b128, broadcast reads (0 bank conflicts measured).
//  - tanh jet: e=exp2(z*2log2e); r=rcp(1+e); t=fma(-2,r,1); d=fma(-t,t,1).
//  - output dot fused into layer-3 activation.

#define H  10
#define RS 12
#define TWO_LOG2E 2.885390082f

typedef float v2f __attribute__((ext_vector_type(2)));

static __device__ __forceinline__ v2f splat(float c) { return (v2f){c, c}; }
static __device__ __forceinline__ v2f pk_fma(v2f a, v2f b, v2f c) {
    return __builtin_elementwise_fma(a, b, c);
}

// packed tanh jet: t = tanh(z), d = sech^2(z), two trans ops per element
#define TANH_TD2(z, t, d)                                   \
    {                                                       \
        const v2f a_ = (z) * splat(TWO_LOG2E);              \
        v2f e_;                                             \
        e_.x = __builtin_amdgcn_exp2f(a_.x);                \
        e_.y = __builtin_amdgcn_exp2f(a_.y);                \
        const v2f w_ = e_ + splat(1.f);                     \
        v2f r_;                                             \
        r_.x = __builtin_amdgcn_rcpf(w_.x);                 \
        r_.y = __builtin_amdgcn_rcpf(w_.y);                 \
        (t) = pk_fma(splat(-2.f), r_, splat(1.f));          \
        (d) = pk_fma(-(t), (t), splat(1.f));                \
    }

__global__
__attribute__((amdgpu_flat_work_group_size(256, 256)))
__attribute__((amdgpu_waves_per_eu(3, 3)))
void pinn_fused(
    const float* __restrict__ x,
    const float* __restrict__ W1, const float* __restrict__ b1,
    const float* __restrict__ W2, const float* __restrict__ b2,
    const float* __restrict__ W3, const float* __restrict__ b3,
    const float* __restrict__ W4,
    float* __restrict__ out, int n)
{
    __shared__ __align__(16) float sW2[H * RS];
    __shared__ __align__(16) float sW3[H * RS];
    __shared__ float sW1[H], sB1[H], sB2[H], sB3[H], sW4[H];

    const int tid = threadIdx.x;
    if (tid < H * RS) {
        const int r = tid / RS, c = tid - r * RS;
        sW2[tid] = (c < H) ? W2[r * H + c] : 0.f;
        sW3[tid] = (c < H) ? W3[r * H + c] : 0.f;
    }
    if (tid < H) {
        sW1[tid] = W1[tid];
        sB1[tid] = b1[tid];
        sB2[tid] = b2[tid];
        sB3[tid] = b3[tid];
        sW4[tid] = W4[tid];
    }
    __syncthreads();

    const int i0 = 2 * (blockIdx.x * 256 + tid);
    if (i0 >= n) return;
    const bool two = (i0 + 1 < n);

    v2f xv;
    if (two) { const float2 t = *(const float2*)(x + i0); xv = (v2f){t.x, t.y}; }
    else     { xv = (v2f){x[i0], 0.f}; }

    // per-node jet state for the sample pair: t (value), g (d/dx), s (d2/dx2)
    v2f t_[H], g_[H], s_[H];

    // ---- layer 1: z = x*w + b ; z' = w ; z'' = 0 ----
    // s1 = -2 t d w^2 = -2 * (t*g) * w with g = d*w
#pragma unroll
    for (int j = 0; j < H; ++j) {
        const float w = sW1[j];
        const v2f z = pk_fma(xv, splat(w), splat(sB1[j]));
        v2f t, d;
        TANH_TD2(z, t, d);
        const v2f g = d * splat(w);
        const v2f y = (t * g) * splat(w);
        t_[j] = t;
        g_[j] = g;
        s_[j] = y * splat(-2.f);
    }

    v2f z_[H], p_[H], q_[H];
#define MATVEC(SW, SB)                                                        \
    {                                                                         \
        {   /* j == 0 folds accumulator init */                               \
            const float4* row = (const float4*)(SW);                          \
            const float4 w0 = row[0], w1v = row[1], w2v = row[2];             \
            const float wr[H] = {w0.x, w0.y, w0.z, w0.w,                      \
                                 w1v.x, w1v.y, w1v.z, w1v.w,                  \
                                 w2v.x, w2v.y};                               \
            const v2f tj = t_[0], gj = g_[0], sj = s_[0];                     \
            _Pragma("unroll")                                                 \
            for (int k = 0; k < H; ++k) {                                     \
                const v2f w = splat(wr[k]);                                   \
                z_[k] = pk_fma(tj, w, splat(SB[k]));                          \
                p_[k] = gj * w;                                               \
                q_[k] = sj * w;                                               \
            }                                                                 \
        }                                                                     \
        _Pragma("unroll")                                                     \
        for (int j = 1; j < H; ++j) {                                         \
            const float4* row = (const float4*)(SW + j * RS);                 \
            const float4 w0 = row[0], w1v = row[1], w2v = row[2];             \
            const float wr[H] = {w0.x, w0.y, w0.z, w0.w,                      \
                                 w1v.x, w1v.y, w1v.z, w1v.w,                  \
                                 w2v.x, w2v.y};                               \
            const v2f tj = t_[j], gj = g_[j], sj = s_[j];                     \
            _Pragma("unroll")                                                 \
            for (int k = 0; k < H; ++k) {                                     \
                const v2f w = splat(wr[k]);                                   \
                z_[k] = pk_fma(tj, w, z_[k]);                                 \
                p_[k] = pk_fma(gj, w, p_[k]);                                 \
                q_[k] = pk_fma(sj, w, q_[k]);                                 \
            }                                                                 \
        }                                                                     \
    }

    // ---- layer 2 matvec + activation jet ----
    MATVEC(sW2, sB2)
#pragma unroll
    for (int k = 0; k < H; ++k) {
        const v2f p = p_[k], q = q_[k];
        v2f t, d;
        TANH_TD2(z_[k], t, d);
        const v2f g = d * p;
        const v2f dq = d * q;
        const v2f m = (t + t) * p;
        t_[k] = t;
        g_[k] = g;
        s_[k] = pk_fma(-m, g, dq);
    }

    // ---- layer 3 matvec + fused activation + output dot ----
    MATVEC(sW3, sB3)
#undef MATVEC

    v2f u = splat(0.f), ux = splat(0.f), uxx = splat(0.f);
#pragma unroll
    for (int k = 0; k < H; ++k) {
        const v2f p = p_[k], q = q_[k];
        v2f t, d;
        TANH_TD2(z_[k], t, d);
        const v2f g = d * p;
        const v2f dq = d * q;
        const v2f m = (t + t) * p;
        const v2f s = pk_fma(-m, g, dq);
        const v2f w = splat(sW4[k]);
        u   = pk_fma(t, w, u);
        ux  = pk_fma(g, w, ux);
        uxx = pk_fma(s, w, uxx);
    }

    float* o = out + i0 * 3;   // 6 floats for the pair, 8B-aligned
    if (two) {
        ((v2f*)o)[0] = (v2f){u.x,   ux.x};
        ((v2f*)o)[1] = (v2f){uxx.x, u.y};
        ((v2f*)o)[2] = (v2f){ux.y,  uxx.y};
    } else {
        o[0] = u.x; o[1] = ux.x; o[2] = uxx.x;
    }
}

extern "C" void kernel_launch(void* const* d_in, const int* in_sizes, int n_in,
                              void* d_out, int out_size, void* d_ws, size_t ws_size,
                              hipStream_t stream) {
    const float* x  = (const float*)d_in[0];
    const float* W1 = (const float*)d_in[1];
    const float* b1 = (const float*)d_in[2];
    const float* W2 = (const float*)d_in[3];
    const float* b2 = (const float*)d_in[4];
    const float* W3 = (const float*)d_in[5];
    const float* b3 = (const float*)d_in[6];
    const float* W4 = (const float*)d_in[7];
    float* out = (float*)d_out;

    const int n = in_sizes[0];
    const int threads = 256;
    const int blocks = (n / 2 + threads - 1) / threads;  // 2 samples/thread
    pinn_fused<<<blocks, threads, 0, stream>>>(x, W1, b1, W2, b2, W3, b3, W4, out, n);
}